// Round 15
// baseline (46.627 us; speedup 1.0000x reference)
//
#include <hip/hip_runtime.h>

#define THREADS 256
#define CPT     4     // coords per thread -> 256 blocks
#define NPMAX   264   // 256 + pad room (multiple-of-8 padding)

typedef __attribute__((ext_vector_type(2))) float f32x2;

static __device__ __forceinline__ f32x2 v2(float v) { f32x2 r; r.x = v; r.y = v; return r; }
static __device__ __forceinline__ f32x2 fmav(f32x2 a, f32x2 b, f32x2 c) {
    return __builtin_elementwise_fma(a, b, c);   // -> v_pk_fma_f32
}

// one particle (pa,pb) against both packed coord groups
#define INTER4(pa, pb) { \
    { \
        f32x2 lx = v2(pa.x) - cxA, ly = v2(pa.y) - cyA, lz = v2(pa.z) - czA; \
        f32x2 d2 = fmav(lx, lx, fmav(ly, ly, lz * lz)); \
        f32x2 arg = d2 * v2(pa.w); \
        f32x2 s; \
        s.x = __builtin_amdgcn_exp2f(arg.x) * __builtin_amdgcn_rsqf(d2.x); \
        s.y = __builtin_amdgcn_exp2f(arg.y) * __builtin_amdgcn_rsqf(d2.y); \
        s.x = (d2.x < pb.w) ? s.x : 0.0f; \
        s.y = (d2.y < pb.w) ? s.y : 0.0f; \
        f32x2 crx = fmav(ly, v2(pb.z), -(lz * v2(pb.y))); \
        f32x2 cry = fmav(lz, v2(pb.x), -(lx * v2(pb.z))); \
        f32x2 crz = fmav(lx, v2(pb.y), -(ly * v2(pb.x))); \
        axA = fmav(s, crx, axA); ayA = fmav(s, cry, ayA); azA = fmav(s, crz, azA); \
    } \
    { \
        f32x2 lx = v2(pa.x) - cxB, ly = v2(pa.y) - cyB, lz = v2(pa.z) - czB; \
        f32x2 d2 = fmav(lx, lx, fmav(ly, ly, lz * lz)); \
        f32x2 arg = d2 * v2(pa.w); \
        f32x2 s; \
        s.x = __builtin_amdgcn_exp2f(arg.x) * __builtin_amdgcn_rsqf(d2.x); \
        s.y = __builtin_amdgcn_exp2f(arg.y) * __builtin_amdgcn_rsqf(d2.y); \
        s.x = (d2.x < pb.w) ? s.x : 0.0f; \
        s.y = (d2.y < pb.w) ? s.y : 0.0f; \
        f32x2 crx = fmav(ly, v2(pb.z), -(lz * v2(pb.y))); \
        f32x2 cry = fmav(lz, v2(pb.x), -(lx * v2(pb.z))); \
        f32x2 crz = fmav(lx, v2(pb.y), -(ly * v2(pb.x))); \
        axB = fmav(s, crx, axB); ayB = fmav(s, cry, ayB); azB = fmav(s, crz, azB); \
    } \
}

// ---------------------------------------------------------------------------
// Prep (1 block): per-particle constants at time_idx, ballot-compacted
// (deterministic stable order) into d_ws, ZERO-PADDED to a multiple of 8
// (pads: pb.w = 0 -> d2 < 0 never true -> exact 0 contribution).
//   pa = {px,py,pz, -log2e/(2r^2)}   pb = {A*dx,A*dy,A*dz, 9r^2}
// ---------------------------------------------------------------------------
__global__ __launch_bounds__(THREADS) void vortex_prep(
        const float* __restrict__ ppos,
        const float* __restrict__ pdir,
        const float* __restrict__ pint,
        const float* __restrict__ iraw,
        const float* __restrict__ rad,
        const int*   __restrict__ tmask,
        const int*   __restrict__ tidxp,
        int P, int T,
        float4* __restrict__ parts,
        int*    __restrict__ dcount) {
    __shared__ int wtot[THREADS / 64];
    const int tid  = threadIdx.x;
    const int lane = tid & 63;
    const int wid  = tid >> 6;
    const int t = *tidxp;

    bool active = false;
    float4 a, b;
    if (tid < P) {
        const int p = tid;
        float m  = (float)tmask[p * T + t];
        float cl = fminf(fmaxf(iraw[p], 0.0f), 10.0f);
        float w  = sqrtf(cl + 1e-8f) * pint[p * T + t] * m;
        float r  = fmaxf(0.2f * (0.5f * rad[p] + 1.0f), 0.0f);
        active   = (w != 0.0f) && (r > 0.0f);
        if (active) {
            const float* pp = ppos + (size_t)(p * T + t) * 3;
            const float* pd = pdir + (size_t)(p * T + t) * 3;
            float A = w / (r * r * r * 40000.0f);
            a = make_float4(pp[0], pp[1], pp[2], -1.442695040888963f / (2.0f * r * r));
            b = make_float4(A * pd[0], A * pd[1], A * pd[2], 9.0f * r * r);
        }
    }
    unsigned long long bm = __ballot(active);
    int pre = __popcll(bm & ((1ull << lane) - 1ull));
    if (lane == 0) wtot[wid] = __popcll(bm);
    __syncthreads();
    int off = 0, tot = 0;
    #pragma unroll
    for (int w2 = 0; w2 < THREADS / 64; ++w2) {
        int c = wtot[w2];
        if (w2 < wid) off += c;
        tot += c;
    }
    if (active) {
        int pos = off + pre;
        parts[2 * pos]     = a;
        parts[2 * pos + 1] = b;
    }
    const int tot_pad = (tot + 7) & ~7;
    if (tid >= tot && tid < tot_pad) {
        float4 z = make_float4(0.f, 0.f, 0.f, 0.f);
        parts[2 * tid]     = z;
        parts[2 * tid + 1] = z;
    }
    if (tid == 0) *dcount = tot_pad;
}

// ---------------------------------------------------------------------------
// Main: CPT=4 packed fp32. Particle constants come via per-lane GLOBAL loads
// with a wave-uniform address (one L1 transaction, 8 KB array L1-resident) —
// the vector-memory pipe replaces the LDS pipe, and global loads are
// compiler-software-pipelined with counted vmcnt across the unrolled loop.
// No LDS use at all.
// ---------------------------------------------------------------------------
__global__ __launch_bounds__(THREADS) void vortex_main(
        const float*  __restrict__ coord,
        const float4* __restrict__ parts,
        const int*    __restrict__ dcount,
        float*        __restrict__ out,
        int N) {
    const int tid = threadIdx.x;
    const int i0 = blockIdx.x * (THREADS * CPT) + tid;
    const int i1 = i0 + THREADS;
    const int i2 = i0 + 2 * THREADS;
    const int i3 = i0 + 3 * THREADS;
    const bool v0 = (i0 < N), v1 = (i1 < N), v2_ = (i2 < N), v3 = (i3 < N);
    f32x2 cxA = v2(0.f), cyA = v2(0.f), czA = v2(0.f);   // coords 0,1
    f32x2 cxB = v2(0.f), cyB = v2(0.f), czB = v2(0.f);   // coords 2,3
    if (v0) { cxA.x = coord[3 * i0]; cyA.x = coord[3 * i0 + 1]; czA.x = coord[3 * i0 + 2]; }
    if (v1) { cxA.y = coord[3 * i1]; cyA.y = coord[3 * i1 + 1]; czA.y = coord[3 * i1 + 2]; }
    if (v2_) { cxB.x = coord[3 * i2]; cyB.x = coord[3 * i2 + 1]; czB.x = coord[3 * i2 + 2]; }
    if (v3) { cxB.y = coord[3 * i3]; cyB.y = coord[3 * i3 + 1]; czB.y = coord[3 * i3 + 2]; }

    const int cnt = __builtin_amdgcn_readfirstlane(*dcount);   // multiple of 8

    f32x2 axA = v2(0.f), ayA = v2(0.f), azA = v2(0.f);
    f32x2 axB = v2(0.f), ayB = v2(0.f), azB = v2(0.f);

    #pragma unroll 8
    for (int p = 0; p < cnt; ++p) {
        const float4 pa = parts[2 * p];
        const float4 pb = parts[2 * p + 1];
        INTER4(pa, pb);
    }

    if (v0) { out[3 * i0] = axA.x; out[3 * i0 + 1] = ayA.x; out[3 * i0 + 2] = azA.x; }
    if (v1) { out[3 * i1] = axA.y; out[3 * i1 + 1] = ayA.y; out[3 * i1 + 2] = azA.y; }
    if (v2_) { out[3 * i2] = axB.x; out[3 * i2 + 1] = ayB.x; out[3 * i2 + 2] = azB.x; }
    if (v3) { out[3 * i3] = axB.y; out[3 * i3 + 1] = ayB.y; out[3 * i3 + 2] = azB.y; }
}

extern "C" void kernel_launch(void* const* d_in, const int* in_sizes, int n_in,
                              void* d_out, int out_size, void* d_ws, size_t ws_size,
                              hipStream_t stream) {
    const float* coord = (const float*)d_in[0];
    const float* ppos  = (const float*)d_in[1];
    const float* pdir  = (const float*)d_in[2];
    const float* pint  = (const float*)d_in[3];
    const float* iraw  = (const float*)d_in[4];
    const float* rad   = (const float*)d_in[5];
    const int*   tmask = (const int*)d_in[6];
    const int*   tidx  = (const int*)d_in[7];
    float* out = (float*)d_out;

    const int N = in_sizes[0] / 3;        // 262144 coords
    const int P = in_sizes[4];            // 256 particles
    const int T = in_sizes[3] / P;        // 8 time steps

    float4* parts = (float4*)d_ws;
    int* dcount   = (int*)((char*)d_ws + (size_t)2 * NPMAX * sizeof(float4));

    hipLaunchKernelGGL(vortex_prep, dim3(1), dim3(THREADS), 0, stream,
                       ppos, pdir, pint, iraw, rad, tmask, tidx, P, T, parts, dcount);

    const int coordsPerBlock = THREADS * CPT;
    const int blocks = (N + coordsPerBlock - 1) / coordsPerBlock;
    hipLaunchKernelGGL(vortex_main, dim3(blocks), dim3(THREADS), 0, stream,
                       coord, parts, dcount, out, N);
}

// Round 16
// 31.199 us; speedup vs baseline: 1.4945x; 1.4945x over previous
//
#include <hip/hip_runtime.h>

#define THREADS 256   // 4 waves/block
#define CPT     4     // coords per thread -> 256 blocks
#define NPMAX   256   // max particles

typedef __attribute__((ext_vector_type(2))) float f32x2;

static __device__ __forceinline__ f32x2 v2(float v) { f32x2 r; r.x = v; r.y = v; return r; }
static __device__ __forceinline__ f32x2 fmav(f32x2 a, f32x2 b, f32x2 c) {
    return __builtin_elementwise_fma(a, b, c);   // -> v_pk_fma_f32
}

// exp2 approx: split int/frac, deg-4 poly on frac (p(0)=1, p(1)=2 forced),
// exponent via bit construction. Valid for x in (-126, 0]; clamped below.
// Max rel err ~5e-5. All poly ops are v_pk_*.
static __device__ __forceinline__ f32x2 exp2_fast(f32x2 x) {
    f32x2 xc = __builtin_elementwise_max(x, v2(-126.0f));
    f32x2 fl; fl.x = floorf(xc.x); fl.y = floorf(xc.y);
    f32x2 t = xc - fl;
    f32x2 p = fmav(fmav(fmav(fmav(v2(0.0111222f), t, v2(0.05550411f)), t,
                             v2(0.24022651f)), t, v2(0.69314718f)), t, v2(1.0f));
    unsigned e0 = (unsigned)((int)fl.x + 127) << 23;
    unsigned e1 = (unsigned)((int)fl.y + 127) << 23;
    f32x2 sc; sc.x = __uint_as_float(e0); sc.y = __uint_as_float(e1);
    return p * sc;
}

// rsqrt approx: magic-constant seed + 1 Newton step. Max rel err ~0.17%.
static __device__ __forceinline__ f32x2 rsq_fast(f32x2 d2) {
    unsigned u0 = 0x5f3759dfu - (__float_as_uint(d2.x) >> 1);
    unsigned u1 = 0x5f3759dfu - (__float_as_uint(d2.y) >> 1);
    f32x2 y; y.x = __uint_as_float(u0); y.y = __uint_as_float(u1);
    f32x2 h = d2 * v2(-0.5f);
    f32x2 t = y * y;
    f32x2 v = fmav(h, t, v2(1.5f));
    return y * v;
}

// one particle (pa,pb) against both packed coord groups — trans-free
#define INTER4(pa, pb) { \
    { \
        f32x2 lx = v2(pa.x) - cxA, ly = v2(pa.y) - cyA, lz = v2(pa.z) - czA; \
        f32x2 d2 = fmav(lx, lx, fmav(ly, ly, lz * lz)); \
        f32x2 s = exp2_fast(d2 * v2(pa.w)) * rsq_fast(d2); \
        s.x = (d2.x < pb.w) ? s.x : 0.0f; \
        s.y = (d2.y < pb.w) ? s.y : 0.0f; \
        f32x2 crx = fmav(ly, v2(pb.z), -(lz * v2(pb.y))); \
        f32x2 cry = fmav(lz, v2(pb.x), -(lx * v2(pb.z))); \
        f32x2 crz = fmav(lx, v2(pb.y), -(ly * v2(pb.x))); \
        axA = fmav(s, crx, axA); ayA = fmav(s, cry, ayA); azA = fmav(s, crz, azA); \
    } \
    { \
        f32x2 lx = v2(pa.x) - cxB, ly = v2(pa.y) - cyB, lz = v2(pa.z) - czB; \
        f32x2 d2 = fmav(lx, lx, fmav(ly, ly, lz * lz)); \
        f32x2 s = exp2_fast(d2 * v2(pa.w)) * rsq_fast(d2); \
        s.x = (d2.x < pb.w) ? s.x : 0.0f; \
        s.y = (d2.y < pb.w) ? s.y : 0.0f; \
        f32x2 crx = fmav(ly, v2(pb.z), -(lz * v2(pb.y))); \
        f32x2 cry = fmav(lz, v2(pb.x), -(lx * v2(pb.z))); \
        f32x2 crz = fmav(lx, v2(pb.y), -(ly * v2(pb.x))); \
        axB = fmav(s, crx, axB); ayB = fmav(s, cry, ayB); azB = fmav(s, crz, azB); \
    } \
}

// ---------------------------------------------------------------------------
// Fused kernel (R12 structure = best): packed fp32, CPT=4, LDS particle
// table, plain unrolled loop. Transcendentals replaced by full-rate
// approximations (error budget: threshold 5.5e-5 ~ 29x current error).
// Constants: pa = {px,py,pz, -log2e/(2r^2)}, pb = {A*dx,A*dy,A*dz, 9r^2}.
// ---------------------------------------------------------------------------
__global__ __launch_bounds__(THREADS) void vortex_fused(
        const float* __restrict__ coord,
        const float* __restrict__ ppos,
        const float* __restrict__ pdir,
        const float* __restrict__ pint,
        const float* __restrict__ iraw,
        const float* __restrict__ rad,
        const int*   __restrict__ tmask,
        const int*   __restrict__ tidxp,
        float*       __restrict__ out,
        int N, int P, int T) {
    __shared__ float4 sp[2 * NPMAX];
    __shared__ int    wtot[THREADS / 64];
    __shared__ int    s_cnt;

    const int tid  = threadIdx.x;
    const int lane = tid & 63;
    const int wid  = tid >> 6;

    // ---- coord loads first so they overlap the prep work ----
    const int i0 = blockIdx.x * (THREADS * CPT) + tid;
    const int i1 = i0 + THREADS;
    const int i2 = i0 + 2 * THREADS;
    const int i3 = i0 + 3 * THREADS;
    const bool v0 = (i0 < N), v1 = (i1 < N), v2_ = (i2 < N), v3 = (i3 < N);
    f32x2 cxA = v2(0.f), cyA = v2(0.f), czA = v2(0.f);   // coords 0,1
    f32x2 cxB = v2(0.f), cyB = v2(0.f), czB = v2(0.f);   // coords 2,3
    if (v0) { cxA.x = coord[3 * i0]; cyA.x = coord[3 * i0 + 1]; czA.x = coord[3 * i0 + 2]; }
    if (v1) { cxA.y = coord[3 * i1]; cyA.y = coord[3 * i1 + 1]; czA.y = coord[3 * i1 + 2]; }
    if (v2_) { cxB.x = coord[3 * i2]; cyB.x = coord[3 * i2 + 1]; czB.x = coord[3 * i2 + 2]; }
    if (v3) { cxB.y = coord[3 * i3]; cyB.y = coord[3 * i3 + 1]; czB.y = coord[3 * i3 + 2]; }

    // ---- per-particle prep + ballot compaction (deterministic order) ----
    const int t = *tidxp;
    bool active = false;
    float4 a, b;
    if (tid < P) {
        const int p = tid;
        float m  = (float)tmask[p * T + t];
        float cl = fminf(fmaxf(iraw[p], 0.0f), 10.0f);
        float w  = sqrtf(cl + 1e-8f) * pint[p * T + t] * m;
        float r  = fmaxf(0.2f * (0.5f * rad[p] + 1.0f), 0.0f);
        active   = (w != 0.0f) && (r > 0.0f);
        if (active) {
            const float* pp = ppos + (size_t)(p * T + t) * 3;
            const float* pd = pdir + (size_t)(p * T + t) * 3;
            float A = w / (r * r * r * 40000.0f);
            a = make_float4(pp[0], pp[1], pp[2], -1.442695040888963f / (2.0f * r * r));
            b = make_float4(A * pd[0], A * pd[1], A * pd[2], 9.0f * r * r);
        }
    }
    unsigned long long bm = __ballot(active);
    int pre = __popcll(bm & ((1ull << lane) - 1ull));
    if (lane == 0) wtot[wid] = __popcll(bm);
    __syncthreads();
    int off = 0, tot = 0;
    #pragma unroll
    for (int w2 = 0; w2 < THREADS / 64; ++w2) {
        int c = wtot[w2];
        if (w2 < wid) off += c;
        tot += c;
    }
    if (active) {
        int pos = off + pre;
        sp[2 * pos]     = a;
        sp[2 * pos + 1] = b;
    }
    if (tid == 0) s_cnt = tot;
    __syncthreads();
    const int cnt = s_cnt;   // uniform across block

    // ---- packed main loop ----
    f32x2 axA = v2(0.f), ayA = v2(0.f), azA = v2(0.f);
    f32x2 axB = v2(0.f), ayB = v2(0.f), azB = v2(0.f);
    #pragma unroll 4
    for (int p = 0; p < cnt; ++p) {
        const float4 pa = sp[2 * p];
        const float4 pb = sp[2 * p + 1];
        INTER4(pa, pb);
    }

    if (v0) { out[3 * i0] = axA.x; out[3 * i0 + 1] = ayA.x; out[3 * i0 + 2] = azA.x; }
    if (v1) { out[3 * i1] = axA.y; out[3 * i1 + 1] = ayA.y; out[3 * i1 + 2] = azA.y; }
    if (v2_) { out[3 * i2] = axB.x; out[3 * i2 + 1] = ayB.x; out[3 * i2 + 2] = azB.x; }
    if (v3) { out[3 * i3] = axB.y; out[3 * i3 + 1] = ayB.y; out[3 * i3 + 2] = azB.y; }
}

extern "C" void kernel_launch(void* const* d_in, const int* in_sizes, int n_in,
                              void* d_out, int out_size, void* d_ws, size_t ws_size,
                              hipStream_t stream) {
    const float* coord = (const float*)d_in[0];
    const float* ppos  = (const float*)d_in[1];
    const float* pdir  = (const float*)d_in[2];
    const float* pint  = (const float*)d_in[3];
    const float* iraw  = (const float*)d_in[4];
    const float* rad   = (const float*)d_in[5];
    const int*   tmask = (const int*)d_in[6];
    const int*   tidx  = (const int*)d_in[7];
    float* out = (float*)d_out;

    const int N = in_sizes[0] / 3;        // 262144 coords
    const int P = in_sizes[4];            // 256 particles (intensity_raw is (P,1))
    const int T = in_sizes[3] / P;        // 8 time steps (particle_intensity is (P,T,1))

    const int coordsPerBlock = THREADS * CPT;
    const int blocks = (N + coordsPerBlock - 1) / coordsPerBlock;
    hipLaunchKernelGGL(vortex_fused, dim3(blocks), dim3(THREADS), 0, stream,
                       coord, ppos, pdir, pint, iraw, rad, tmask, tidx, out, N, P, T);
}

// Round 17
// 26.957 us; speedup vs baseline: 1.7297x; 1.1573x over previous
//
#include <hip/hip_runtime.h>

#define THREADS 256   // 4 waves/block
#define CPT     4     // coords per thread; grid (256 chunks) x (2 teams)
#define NPMAX   256   // max particles

typedef __attribute__((ext_vector_type(2))) float f32x2;

static __device__ __forceinline__ f32x2 v2(float v) { f32x2 r; r.x = v; r.y = v; return r; }
static __device__ __forceinline__ f32x2 fmav(f32x2 a, f32x2 b, f32x2 c) {
    return __builtin_elementwise_fma(a, b, c);   // -> v_pk_fma_f32
}

// one particle (pa,pb) against both packed coord groups (exact math, R12)
#define INTER4(pa, pb) { \
    { \
        f32x2 lx = v2(pa.x) - cxA, ly = v2(pa.y) - cyA, lz = v2(pa.z) - czA; \
        f32x2 d2 = fmav(lx, lx, fmav(ly, ly, lz * lz)); \
        f32x2 arg = d2 * v2(pa.w); \
        f32x2 s; \
        s.x = __builtin_amdgcn_exp2f(arg.x) * __builtin_amdgcn_rsqf(d2.x); \
        s.y = __builtin_amdgcn_exp2f(arg.y) * __builtin_amdgcn_rsqf(d2.y); \
        s.x = (d2.x < pb.w) ? s.x : 0.0f; \
        s.y = (d2.y < pb.w) ? s.y : 0.0f; \
        f32x2 crx = fmav(ly, v2(pb.z), -(lz * v2(pb.y))); \
        f32x2 cry = fmav(lz, v2(pb.x), -(lx * v2(pb.z))); \
        f32x2 crz = fmav(lx, v2(pb.y), -(ly * v2(pb.x))); \
        axA = fmav(s, crx, axA); ayA = fmav(s, cry, ayA); azA = fmav(s, crz, azA); \
    } \
    { \
        f32x2 lx = v2(pa.x) - cxB, ly = v2(pa.y) - cyB, lz = v2(pa.z) - czB; \
        f32x2 d2 = fmav(lx, lx, fmav(ly, ly, lz * lz)); \
        f32x2 arg = d2 * v2(pa.w); \
        f32x2 s; \
        s.x = __builtin_amdgcn_exp2f(arg.x) * __builtin_amdgcn_rsqf(d2.x); \
        s.y = __builtin_amdgcn_exp2f(arg.y) * __builtin_amdgcn_rsqf(d2.y); \
        s.x = (d2.x < pb.w) ? s.x : 0.0f; \
        s.y = (d2.y < pb.w) ? s.y : 0.0f; \
        f32x2 crx = fmav(ly, v2(pb.z), -(lz * v2(pb.y))); \
        f32x2 cry = fmav(lz, v2(pb.x), -(lx * v2(pb.z))); \
        f32x2 crz = fmav(lx, v2(pb.y), -(ly * v2(pb.x))); \
        axB = fmav(s, crx, axB); ayB = fmav(s, cry, ayB); azB = fmav(s, crz, azB); \
    } \
}

// ---------------------------------------------------------------------------
// Team kernel: grid (256, 2). blockIdx.y = team; each team sums HALF the
// compacted particle list over the same CPT=4 coords and writes partial sums
// to its own buffer. 512 blocks -> 2 blocks/CU -> 2 waves/SIMD (fixes the
// 1-wave/SIMD stall exposure of plain CPT=4) while keeping CPT=4's LDS
// amortization (each team reads only its half of the particles).
// Constants: pa = {px,py,pz, -log2e/(2r^2)}, pb = {A*dx,A*dy,A*dz, 9r^2}.
// ---------------------------------------------------------------------------
__global__ __launch_bounds__(THREADS) void vortex_team(
        const float* __restrict__ coord,
        const float* __restrict__ ppos,
        const float* __restrict__ pdir,
        const float* __restrict__ pint,
        const float* __restrict__ iraw,
        const float* __restrict__ rad,
        const int*   __restrict__ tmask,
        const int*   __restrict__ tidxp,
        float*       __restrict__ bufA,   // team 0 partials
        float*       __restrict__ bufB,   // team 1 partials
        int N, int P, int T) {
    __shared__ float4 sp[2 * NPMAX];
    __shared__ int    wtot[THREADS / 64];
    __shared__ int    s_cnt;

    const int tid  = threadIdx.x;
    const int lane = tid & 63;
    const int wid  = tid >> 6;
    const int team = blockIdx.y;

    // ---- coord loads first so they overlap the prep work ----
    const int i0 = blockIdx.x * (THREADS * CPT) + tid;
    const int i1 = i0 + THREADS;
    const int i2 = i0 + 2 * THREADS;
    const int i3 = i0 + 3 * THREADS;
    const bool v0 = (i0 < N), v1 = (i1 < N), v2_ = (i2 < N), v3 = (i3 < N);
    f32x2 cxA = v2(0.f), cyA = v2(0.f), czA = v2(0.f);   // coords 0,1
    f32x2 cxB = v2(0.f), cyB = v2(0.f), czB = v2(0.f);   // coords 2,3
    if (v0) { cxA.x = coord[3 * i0]; cyA.x = coord[3 * i0 + 1]; czA.x = coord[3 * i0 + 2]; }
    if (v1) { cxA.y = coord[3 * i1]; cyA.y = coord[3 * i1 + 1]; czA.y = coord[3 * i1 + 2]; }
    if (v2_) { cxB.x = coord[3 * i2]; cyB.x = coord[3 * i2 + 1]; czB.x = coord[3 * i2 + 2]; }
    if (v3) { cxB.y = coord[3 * i3]; cyB.y = coord[3 * i3 + 1]; czB.y = coord[3 * i3 + 2]; }

    // ---- per-particle prep + ballot compaction (deterministic order) ----
    const int t = *tidxp;
    bool active = false;
    float4 a, b;
    if (tid < P) {
        const int p = tid;
        float m  = (float)tmask[p * T + t];
        float cl = fminf(fmaxf(iraw[p], 0.0f), 10.0f);
        float w  = sqrtf(cl + 1e-8f) * pint[p * T + t] * m;
        float r  = fmaxf(0.2f * (0.5f * rad[p] + 1.0f), 0.0f);
        active   = (w != 0.0f) && (r > 0.0f);
        if (active) {
            const float* pp = ppos + (size_t)(p * T + t) * 3;
            const float* pd = pdir + (size_t)(p * T + t) * 3;
            float A = w / (r * r * r * 40000.0f);
            a = make_float4(pp[0], pp[1], pp[2], -1.442695040888963f / (2.0f * r * r));
            b = make_float4(A * pd[0], A * pd[1], A * pd[2], 9.0f * r * r);
        }
    }
    unsigned long long bm = __ballot(active);
    int pre = __popcll(bm & ((1ull << lane) - 1ull));
    if (lane == 0) wtot[wid] = __popcll(bm);
    __syncthreads();
    int off = 0, tot = 0;
    #pragma unroll
    for (int w2 = 0; w2 < THREADS / 64; ++w2) {
        int c = wtot[w2];
        if (w2 < wid) off += c;
        tot += c;
    }
    if (active) {
        int pos = off + pre;
        sp[2 * pos]     = a;
        sp[2 * pos + 1] = b;
    }
    if (tid == 0) s_cnt = tot;
    __syncthreads();
    const int cnt = s_cnt;                 // uniform
    const int h   = (cnt + 1) >> 1;
    const int p0  = team ? h : 0;          // this team's particle range
    const int p1  = team ? cnt : h;

    // ---- packed main loop over this team's half ----
    f32x2 axA = v2(0.f), ayA = v2(0.f), azA = v2(0.f);
    f32x2 axB = v2(0.f), ayB = v2(0.f), azB = v2(0.f);
    #pragma unroll 4
    for (int p = p0; p < p1; ++p) {
        const float4 pa = sp[2 * p];
        const float4 pb = sp[2 * p + 1];
        INTER4(pa, pb);
    }

    float* buf = team ? bufB : bufA;
    if (v0) { buf[3 * i0] = axA.x; buf[3 * i0 + 1] = ayA.x; buf[3 * i0 + 2] = azA.x; }
    if (v1) { buf[3 * i1] = axA.y; buf[3 * i1 + 1] = ayA.y; buf[3 * i1 + 2] = azA.y; }
    if (v2_) { buf[3 * i2] = axB.x; buf[3 * i2 + 1] = ayB.x; buf[3 * i2 + 2] = azB.x; }
    if (v3) { buf[3 * i3] = axB.y; buf[3 * i3 + 1] = ayB.y; buf[3 * i3 + 2] = azB.y; }
}

// ---------------------------------------------------------------------------
// Merge: out = bufA + bufB (float4-vectorized; 3*N floats divisible by 4
// when N % 4 == 0; tail guard for safety).
// ---------------------------------------------------------------------------
__global__ __launch_bounds__(THREADS) void vortex_merge(
        const float* __restrict__ bufA,
        const float* __restrict__ bufB,
        float* __restrict__ out, int total) {
    const int i = blockIdx.x * THREADS + threadIdx.x;
    const int q = total >> 2;
    if (i < q) {
        float4 va = ((const float4*)bufA)[i];
        float4 vb = ((const float4*)bufB)[i];
        ((float4*)out)[i] = make_float4(va.x + vb.x, va.y + vb.y,
                                        va.z + vb.z, va.w + vb.w);
    }
    const int r = (q << 2) + i;
    if (i < (total & 3)) out[r] = bufA[r] + bufB[r];
}

extern "C" void kernel_launch(void* const* d_in, const int* in_sizes, int n_in,
                              void* d_out, int out_size, void* d_ws, size_t ws_size,
                              hipStream_t stream) {
    const float* coord = (const float*)d_in[0];
    const float* ppos  = (const float*)d_in[1];
    const float* pdir  = (const float*)d_in[2];
    const float* pint  = (const float*)d_in[3];
    const float* iraw  = (const float*)d_in[4];
    const float* rad   = (const float*)d_in[5];
    const int*   tmask = (const int*)d_in[6];
    const int*   tidx  = (const int*)d_in[7];
    float* out = (float*)d_out;

    const int N = in_sizes[0] / 3;        // 262144 coords
    const int P = in_sizes[4];            // 256 particles
    const int T = in_sizes[3] / P;        // 8 time steps

    float* bufA = (float*)d_ws;                              // 3 MB
    float* bufB = (float*)((char*)d_ws + (size_t)(4 << 20)); // 3 MB @ 4MB

    const int chunks = (N + THREADS * CPT - 1) / (THREADS * CPT);   // 256
    hipLaunchKernelGGL(vortex_team, dim3(chunks, 2), dim3(THREADS), 0, stream,
                       coord, ppos, pdir, pint, iraw, rad, tmask, tidx,
                       bufA, bufB, N, P, T);

    const int total = 3 * N;
    const int mblocks = (total / 4 + THREADS - 1) / THREADS;
    hipLaunchKernelGGL(vortex_merge, dim3(mblocks), dim3(THREADS), 0, stream,
                       bufA, bufB, out, total);
}

// Round 19
// 26.488 us; speedup vs baseline: 1.7603x; 1.0177x over previous
//
#include <hip/hip_runtime.h>

#define THREADS 256   // 4 waves/block
#define CPT     4     // coords per thread -> 256 blocks
#define NPMAX   256   // max particles

typedef __attribute__((ext_vector_type(2))) float f32x2;

static __device__ __forceinline__ f32x2 v2(float v) { f32x2 r; r.x = v; r.y = v; return r; }
static __device__ __forceinline__ f32x2 fmav(f32x2 a, f32x2 b, f32x2 c) {
    return __builtin_elementwise_fma(a, b, c);   // -> v_pk_fma_f32
}
// wave-uniform broadcast from lane l (VALU pipe, no LDS)
static __device__ __forceinline__ float bcast(float v, int l) {
    return __int_as_float(__builtin_amdgcn_readlane(__float_as_int(v), l));
}

struct PT { float4 a, b; };   // one particle in this lane's registers

// one particle (8 uniform scalars) against both packed coord groups
#define INTER4S(pax, pay, paz, paw, pbx, pby, pbz, pbw) { \
    { \
        f32x2 lx = v2(pax) - cxA, ly = v2(pay) - cyA, lz = v2(paz) - czA; \
        f32x2 d2 = fmav(lx, lx, fmav(ly, ly, lz * lz)); \
        f32x2 arg = d2 * v2(paw); \
        f32x2 s; \
        s.x = __builtin_amdgcn_exp2f(arg.x) * __builtin_amdgcn_rsqf(d2.x); \
        s.y = __builtin_amdgcn_exp2f(arg.y) * __builtin_amdgcn_rsqf(d2.y); \
        s.x = (d2.x < pbw) ? s.x : 0.0f; \
        s.y = (d2.y < pbw) ? s.y : 0.0f; \
        f32x2 crx = fmav(ly, v2(pbz), -(lz * v2(pby))); \
        f32x2 cry = fmav(lz, v2(pbx), -(lx * v2(pbz))); \
        f32x2 crz = fmav(lx, v2(pby), -(ly * v2(pbx))); \
        axA = fmav(s, crx, axA); ayA = fmav(s, cry, ayA); azA = fmav(s, crz, azA); \
    } \
    { \
        f32x2 lx = v2(pax) - cxB, ly = v2(pay) - cyB, lz = v2(paz) - czB; \
        f32x2 d2 = fmav(lx, lx, fmav(ly, ly, lz * lz)); \
        f32x2 arg = d2 * v2(paw); \
        f32x2 s; \
        s.x = __builtin_amdgcn_exp2f(arg.x) * __builtin_amdgcn_rsqf(d2.x); \
        s.y = __builtin_amdgcn_exp2f(arg.y) * __builtin_amdgcn_rsqf(d2.y); \
        s.x = (d2.x < pbw) ? s.x : 0.0f; \
        s.y = (d2.y < pbw) ? s.y : 0.0f; \
        f32x2 crx = fmav(ly, v2(pbz), -(lz * v2(pby))); \
        f32x2 cry = fmav(lz, v2(pbx), -(lx * v2(pbz))); \
        f32x2 crz = fmav(lx, v2(pby), -(ly * v2(pbx))); \
        axB = fmav(s, crx, axB); ayB = fmav(s, cry, ayB); azB = fmav(s, crz, azB); \
    } \
}

// 64 particles from one register bank, broadcast by readlane (uniform i)
#define BANK(T) \
    _Pragma("unroll 4") \
    for (int i = 0; i < 64; ++i) { \
        float pax = bcast(T.a.x, i), pay = bcast(T.a.y, i); \
        float paz = bcast(T.a.z, i), paw = bcast(T.a.w, i); \
        float pbx = bcast(T.b.x, i), pby = bcast(T.b.y, i); \
        float pbz = bcast(T.b.z, i), pbw = bcast(T.b.w, i); \
        INTER4S(pax, pay, paz, paw, pbx, pby, pbz, pbw); \
    }

// ---------------------------------------------------------------------------
// Fused kernel: prep+compaction in LDS (one-time), then each WAVE stages the
// zero-padded particle table into its own VGPRs (4 banks x 8 floats; lane l
// holds particle l+64*bank) and the hot loop broadcasts via v_readlane —
// ZERO LDS traffic per iteration; the CU-shared LDS pipe is off the critical
// path, leaving only per-SIMD VALU/trans throughput.
// Constants: pa = {px,py,pz, -log2e/(2r^2)}, pb = {A*dx,A*dy,A*dz, 9r^2}.
// ---------------------------------------------------------------------------
__global__ __launch_bounds__(THREADS) void vortex_fused(
        const float* __restrict__ coord,
        const float* __restrict__ ppos,
        const float* __restrict__ pdir,
        const float* __restrict__ pint,
        const float* __restrict__ iraw,
        const float* __restrict__ rad,
        const int*   __restrict__ tmask,
        const int*   __restrict__ tidxp,
        float*       __restrict__ out,
        int N, int P, int T) {
    __shared__ float4 sp[2 * NPMAX];
    __shared__ int    wtot[THREADS / 64];
    __shared__ int    s_cnt;

    const int tid  = threadIdx.x;
    const int lane = tid & 63;
    const int wid  = tid >> 6;

    // ---- coord loads first so they overlap the prep work ----
    const int i0 = blockIdx.x * (THREADS * CPT) + tid;
    const int i1 = i0 + THREADS;
    const int i2 = i0 + 2 * THREADS;
    const int i3 = i0 + 3 * THREADS;
    const bool v0 = (i0 < N), v1 = (i1 < N), v2_ = (i2 < N), v3 = (i3 < N);
    f32x2 cxA = v2(0.f), cyA = v2(0.f), czA = v2(0.f);   // coords 0,1
    f32x2 cxB = v2(0.f), cyB = v2(0.f), czB = v2(0.f);   // coords 2,3
    if (v0) { cxA.x = coord[3 * i0]; cyA.x = coord[3 * i0 + 1]; czA.x = coord[3 * i0 + 2]; }
    if (v1) { cxA.y = coord[3 * i1]; cyA.y = coord[3 * i1 + 1]; czA.y = coord[3 * i1 + 2]; }
    if (v2_) { cxB.x = coord[3 * i2]; cyB.x = coord[3 * i2 + 1]; czB.x = coord[3 * i2 + 2]; }
    if (v3) { cxB.y = coord[3 * i3]; cyB.y = coord[3 * i3 + 1]; czB.y = coord[3 * i3 + 2]; }

    // ---- per-particle prep + ballot compaction (deterministic order) ----
    const int t = *tidxp;
    bool active = false;
    float4 a, b;
    if (tid < P) {
        const int p = tid;
        float m  = (float)tmask[p * T + t];
        float cl = fminf(fmaxf(iraw[p], 0.0f), 10.0f);
        float w  = sqrtf(cl + 1e-8f) * pint[p * T + t] * m;
        float r  = fmaxf(0.2f * (0.5f * rad[p] + 1.0f), 0.0f);
        active   = (w != 0.0f) && (r > 0.0f);
        if (active) {
            const float* pp = ppos + (size_t)(p * T + t) * 3;
            const float* pd = pdir + (size_t)(p * T + t) * 3;
            float A = w / (r * r * r * 40000.0f);
            a = make_float4(pp[0], pp[1], pp[2], -1.442695040888963f / (2.0f * r * r));
            b = make_float4(A * pd[0], A * pd[1], A * pd[2], 9.0f * r * r);
        }
    }
    unsigned long long bm = __ballot(active);
    int pre = __popcll(bm & ((1ull << lane) - 1ull));
    if (lane == 0) wtot[wid] = __popcll(bm);
    __syncthreads();
    int off = 0, tot = 0;
    #pragma unroll
    for (int w2 = 0; w2 < THREADS / 64; ++w2) {
        int c = wtot[w2];
        if (w2 < wid) off += c;
        tot += c;
    }
    if (active) {
        int pos = off + pre;
        sp[2 * pos]     = a;
        sp[2 * pos + 1] = b;
    }
    // zero-pad to 256 entries (zero particle: pb.w=0 -> d2<0 never -> exact 0)
    if (tid >= tot) {
        float4 z = make_float4(0.f, 0.f, 0.f, 0.f);
        sp[2 * tid]     = z;
        sp[2 * tid + 1] = z;
    }
    if (tid == 0) s_cnt = tot;
    __syncthreads();
    const int cnt_pad = (s_cnt + 63) & ~63;   // uniform, multiple of 64

    // ---- one-time stage: table into this wave's registers (4 banks) ----
    PT t0, t1, t2, t3;
    t0.a = sp[2 * lane];           t0.b = sp[2 * lane + 1];
    t1.a = sp[2 * (lane + 64)];    t1.b = sp[2 * (lane + 64) + 1];
    t2.a = sp[2 * (lane + 128)];   t2.b = sp[2 * (lane + 128) + 1];
    t3.a = sp[2 * (lane + 192)];   t3.b = sp[2 * (lane + 192) + 1];

    // ---- LDS-free main loop: readlane broadcast + packed fp32 ----
    f32x2 axA = v2(0.f), ayA = v2(0.f), azA = v2(0.f);
    f32x2 axB = v2(0.f), ayB = v2(0.f), azB = v2(0.f);

    BANK(t0);
    if (cnt_pad > 64)  { BANK(t1); }
    if (cnt_pad > 128) { BANK(t2); }
    if (cnt_pad > 192) { BANK(t3); }

    if (v0) { out[3 * i0] = axA.x; out[3 * i0 + 1] = ayA.x; out[3 * i0 + 2] = azA.x; }
    if (v1) { out[3 * i1] = axA.y; out[3 * i1 + 1] = ayA.y; out[3 * i1 + 2] = azA.y; }
    if (v2_) { out[3 * i2] = axB.x; out[3 * i2 + 1] = ayB.x; out[3 * i2 + 2] = azB.x; }
    if (v3) { out[3 * i3] = axB.y; out[3 * i3 + 1] = ayB.y; out[3 * i3 + 2] = azB.y; }
}

extern "C" void kernel_launch(void* const* d_in, const int* in_sizes, int n_in,
                              void* d_out, int out_size, void* d_ws, size_t ws_size,
                              hipStream_t stream) {
    const float* coord = (const float*)d_in[0];
    const float* ppos  = (const float*)d_in[1];
    const float* pdir  = (const float*)d_in[2];
    const float* pint  = (const float*)d_in[3];
    const float* iraw  = (const float*)d_in[4];
    const float* rad   = (const float*)d_in[5];
    const int*   tmask = (const int*)d_in[6];
    const int*   tidx  = (const int*)d_in[7];
    float* out = (float*)d_out;

    const int N = in_sizes[0] / 3;        // 262144 coords
    const int P = in_sizes[4];            // 256 particles (intensity_raw is (P,1))
    const int T = in_sizes[3] / P;        // 8 time steps (particle_intensity is (P,T,1))

    const int coordsPerBlock = THREADS * CPT;
    const int blocks = (N + coordsPerBlock - 1) / coordsPerBlock;
    hipLaunchKernelGGL(vortex_fused, dim3(blocks), dim3(THREADS), 0, stream,
                       coord, ppos, pdir, pint, iraw, rad, tmask, tidx, out, N, P, T);
}

// Round 20
// 25.010 us; speedup vs baseline: 1.8644x; 1.0591x over previous
//
#include <hip/hip_runtime.h>

#define THREADS 256   // 4 waves/block
#define CPT     4     // coords per thread -> 256 blocks, 1 block/CU
#define NPMAX   256   // max particles

typedef __attribute__((ext_vector_type(2))) float f32x2;

static __device__ __forceinline__ f32x2 v2(float v) { f32x2 r; r.x = v; r.y = v; return r; }
static __device__ __forceinline__ f32x2 fmav(f32x2 a, f32x2 b, f32x2 c) {
    return __builtin_elementwise_fma(a, b, c);   // -> v_pk_fma_f32
}

// ---------------------------------------------------------------------------
// Fused kernel, packed-fp32 inner loop, CPT=4: each thread owns 4 coords as
// TWO f32x2 packed groups, so the 2 LDS reads per particle are amortized over
// 4 coords. Best measured configuration (23.44 us, R12).
// Per-particle constants: pa = {px,py,pz, -log2e/(2r^2)}, pb = {A*dx,A*dy,A*dz, 9r^2}.
// inner: each = exp2(d2*pa.w) * rsq(d2) * cross(loc, pb.xyz)  if d2 < pb.w
// ---------------------------------------------------------------------------
__global__ __launch_bounds__(THREADS) void vortex_fused(
        const float* __restrict__ coord,
        const float* __restrict__ ppos,
        const float* __restrict__ pdir,
        const float* __restrict__ pint,
        const float* __restrict__ iraw,
        const float* __restrict__ rad,
        const int*   __restrict__ tmask,
        const int*   __restrict__ tidxp,
        float*       __restrict__ out,
        int N, int P, int T) {
    __shared__ float4 sp[2 * NPMAX];
    __shared__ int    wtot[THREADS / 64];
    __shared__ int    s_cnt;

    const int tid  = threadIdx.x;
    const int lane = tid & 63;
    const int wid  = tid >> 6;

    // ---- coord loads first so they overlap the prep work ----
    const int i0 = blockIdx.x * (THREADS * CPT) + tid;
    const int i1 = i0 + THREADS;
    const int i2 = i0 + 2 * THREADS;
    const int i3 = i0 + 3 * THREADS;
    const bool v0 = (i0 < N), v1 = (i1 < N), v2_ = (i2 < N), v3 = (i3 < N);
    f32x2 cxA = v2(0.f), cyA = v2(0.f), czA = v2(0.f);   // coords 0,1
    f32x2 cxB = v2(0.f), cyB = v2(0.f), czB = v2(0.f);   // coords 2,3
    if (v0) { cxA.x = coord[3 * i0]; cyA.x = coord[3 * i0 + 1]; czA.x = coord[3 * i0 + 2]; }
    if (v1) { cxA.y = coord[3 * i1]; cyA.y = coord[3 * i1 + 1]; czA.y = coord[3 * i1 + 2]; }
    if (v2_) { cxB.x = coord[3 * i2]; cyB.x = coord[3 * i2 + 1]; czB.x = coord[3 * i2 + 2]; }
    if (v3) { cxB.y = coord[3 * i3]; cyB.y = coord[3 * i3 + 1]; czB.y = coord[3 * i3 + 2]; }

    // ---- per-particle prep + ballot compaction (deterministic order) ----
    const int t = *tidxp;
    bool active = false;
    float4 a, b;
    if (tid < P) {
        const int p = tid;
        float m  = (float)tmask[p * T + t];
        float cl = fminf(fmaxf(iraw[p], 0.0f), 10.0f);
        float w  = sqrtf(cl + 1e-8f) * pint[p * T + t] * m;
        float r  = fmaxf(0.2f * (0.5f * rad[p] + 1.0f), 0.0f);
        active   = (w != 0.0f) && (r > 0.0f);
        if (active) {
            const float* pp = ppos + (size_t)(p * T + t) * 3;
            const float* pd = pdir + (size_t)(p * T + t) * 3;
            float A = w / (r * r * r * 40000.0f);
            a = make_float4(pp[0], pp[1], pp[2], -1.442695040888963f / (2.0f * r * r));
            b = make_float4(A * pd[0], A * pd[1], A * pd[2], 9.0f * r * r);
        }
    }
    unsigned long long bm = __ballot(active);
    int pre = __popcll(bm & ((1ull << lane) - 1ull));
    if (lane == 0) wtot[wid] = __popcll(bm);
    __syncthreads();
    int off = 0, tot = 0;
    #pragma unroll
    for (int w2 = 0; w2 < THREADS / 64; ++w2) {
        int c = wtot[w2];
        if (w2 < wid) off += c;
        tot += c;
    }
    if (active) {
        int pos = off + pre;
        sp[2 * pos]     = a;
        sp[2 * pos + 1] = b;
    }
    if (tid == 0) s_cnt = tot;
    __syncthreads();
    const int cnt = s_cnt;   // uniform across block

    // ---- packed main loop: 2 LDS reads serve 4 coords ----
    f32x2 axA = v2(0.f), ayA = v2(0.f), azA = v2(0.f);
    f32x2 axB = v2(0.f), ayB = v2(0.f), azB = v2(0.f);
    #pragma unroll 4
    for (int p = 0; p < cnt; ++p) {
        const float4 pa = sp[2 * p];
        const float4 pb = sp[2 * p + 1];
        {   // group A (coords 0,1)
            f32x2 lx = v2(pa.x) - cxA;
            f32x2 ly = v2(pa.y) - cyA;
            f32x2 lz = v2(pa.z) - czA;
            f32x2 d2 = fmav(lx, lx, fmav(ly, ly, lz * lz));
            f32x2 arg = d2 * v2(pa.w);
            f32x2 s;
            s.x = __builtin_amdgcn_exp2f(arg.x) * __builtin_amdgcn_rsqf(d2.x);
            s.y = __builtin_amdgcn_exp2f(arg.y) * __builtin_amdgcn_rsqf(d2.y);
            s.x = (d2.x < pb.w) ? s.x : 0.0f;
            s.y = (d2.y < pb.w) ? s.y : 0.0f;
            f32x2 crx = fmav(ly, v2(pb.z), -(lz * v2(pb.y)));
            f32x2 cry = fmav(lz, v2(pb.x), -(lx * v2(pb.z)));
            f32x2 crz = fmav(lx, v2(pb.y), -(ly * v2(pb.x)));
            axA = fmav(s, crx, axA);
            ayA = fmav(s, cry, ayA);
            azA = fmav(s, crz, azA);
        }
        {   // group B (coords 2,3)
            f32x2 lx = v2(pa.x) - cxB;
            f32x2 ly = v2(pa.y) - cyB;
            f32x2 lz = v2(pa.z) - czB;
            f32x2 d2 = fmav(lx, lx, fmav(ly, ly, lz * lz));
            f32x2 arg = d2 * v2(pa.w);
            f32x2 s;
            s.x = __builtin_amdgcn_exp2f(arg.x) * __builtin_amdgcn_rsqf(d2.x);
            s.y = __builtin_amdgcn_exp2f(arg.y) * __builtin_amdgcn_rsqf(d2.y);
            s.x = (d2.x < pb.w) ? s.x : 0.0f;
            s.y = (d2.y < pb.w) ? s.y : 0.0f;
            f32x2 crx = fmav(ly, v2(pb.z), -(lz * v2(pb.y)));
            f32x2 cry = fmav(lz, v2(pb.x), -(lx * v2(pb.z)));
            f32x2 crz = fmav(lx, v2(pb.y), -(ly * v2(pb.x)));
            axB = fmav(s, crx, axB);
            ayB = fmav(s, cry, ayB);
            azB = fmav(s, crz, azB);
        }
    }

    if (v0) { out[3 * i0] = axA.x; out[3 * i0 + 1] = ayA.x; out[3 * i0 + 2] = azA.x; }
    if (v1) { out[3 * i1] = axA.y; out[3 * i1 + 1] = ayA.y; out[3 * i1 + 2] = azA.y; }
    if (v2_) { out[3 * i2] = axB.x; out[3 * i2 + 1] = ayB.x; out[3 * i2 + 2] = azB.x; }
    if (v3) { out[3 * i3] = axB.y; out[3 * i3 + 1] = ayB.y; out[3 * i3 + 2] = azB.y; }
}

extern "C" void kernel_launch(void* const* d_in, const int* in_sizes, int n_in,
                              void* d_out, int out_size, void* d_ws, size_t ws_size,
                              hipStream_t stream) {
    const float* coord = (const float*)d_in[0];
    const float* ppos  = (const float*)d_in[1];
    const float* pdir  = (const float*)d_in[2];
    const float* pint  = (const float*)d_in[3];
    const float* iraw  = (const float*)d_in[4];
    const float* rad   = (const float*)d_in[5];
    const int*   tmask = (const int*)d_in[6];
    const int*   tidx  = (const int*)d_in[7];
    float* out = (float*)d_out;

    const int N = in_sizes[0] / 3;        // 262144 coords
    const int P = in_sizes[4];            // 256 particles (intensity_raw is (P,1))
    const int T = in_sizes[3] / P;        // 8 time steps (particle_intensity is (P,T,1))

    const int coordsPerBlock = THREADS * CPT;
    const int blocks = (N + coordsPerBlock - 1) / coordsPerBlock;
    hipLaunchKernelGGL(vortex_fused, dim3(blocks), dim3(THREADS), 0, stream,
                       coord, ppos, pdir, pint, iraw, rad, tmask, tidx, out, N, P, T);
}